// Round 13
// baseline (137.410 us; speedup 1.0000x reference)
//
#include <hip/hip_runtime.h>
#include <math.h>

#define BATCH  4
#define SEQ    4096
#define DIM    128
#define NROW   (BATCH*SEQ)
#define NSPLIT 4
#define NW     384   // concatenated W cols (q|k|v)

typedef _Float16 f16_t;
typedef _Float16 f16x2  __attribute__((ext_vector_type(2)));
typedef _Float16 f16x4  __attribute__((ext_vector_type(4)));
typedef _Float16 f16x8  __attribute__((ext_vector_type(8)));
typedef _Float16 f16x16 __attribute__((ext_vector_type(16)));
typedef float    f32x4  __attribute__((ext_vector_type(4)));
typedef float    f32x16 __attribute__((ext_vector_type(16)));

// softmax scale 1/sqrt(128) and log2(e) folded into Q
#define QSCALE ((float)(1.4426950408889634 / 11.313708498984761))

// ---------------------------------------------------------------------------
// Kernel 0: transpose+hi/lo-split W once: Wt[n][k] = W[k][n] as f16 h/l.
// ---------------------------------------------------------------------------
__global__ __launch_bounds__(256) void wsplit_kernel(
    const float* __restrict__ wq, const float* __restrict__ wk,
    const float* __restrict__ wv,
    f16_t* __restrict__ Wth, f16_t* __restrict__ Wtl)
{
    const int idx = blockIdx.x*256 + threadIdx.x;   // 49152 = 384*128
    const int n = idx >> 7;
    const int k = idx & 127;
    const int mat = n >> 7, col = n & 127;
    const float* w = (mat == 0) ? wq : ((mat == 1) ? wk : wv);
    const float v = w[k*DIM + col];
    const f16_t h = (f16_t)v;
    Wth[idx] = h;
    Wtl[idx] = (f16_t)(v - (float)h);
}

// ---------------------------------------------------------------------------
// Kernel 1: QKV projection as MFMA GEMM (3-term compensated, fp32-accurate).
// LDS 53248 B (3 blocks/CU), phase-1 register prefetch.
// ---------------------------------------------------------------------------
#define LDXX 72   // X staging stride (144B, b128 frag reads)
#define LDW  68   // W staging stride (136B, 2xb64 frag reads)
#define LDE 136   // epilogue transpose stride

__global__ __launch_bounds__(256, 3) void proj_kernel(
    const float* __restrict__ x,
    const f16_t* __restrict__ Wth, const f16_t* __restrict__ Wtl,
    f16_t* __restrict__ Qh, f16_t* __restrict__ Kh, f16_t* __restrict__ Vt)
{
    __shared__ __align__(16) f16_t smem[(64+64)*LDXX + (128+128)*LDW]; // 53248 B
    f16_t* sXh = smem;
    f16_t* sXl = smem + 64*LDXX;
    f16_t* sWh = smem + 128*LDXX;
    f16_t* sWl = smem + 128*LDXX + 128*LDW;

    const int tid  = threadIdx.x;
    const int wave = tid >> 6;
    const int lane = tid & 63;
    const int quad = lane >> 4;
    const int ln   = lane & 15;

    const int nt = blockIdx.x % 3;          // 0=Q 1=K 2=V
    const int mb = blockIdx.x / 3;
    const int m0 = mb * 64;
    const int n0 = nt * 128;

    f32x4 acc[8];
    #pragma unroll
    for (int nb = 0; nb < 8; nb++)
        for (int r = 0; r < 4; r++) acc[nb][r] = 0.f;

    float4 px[4]; uint4 pwh[4], pwl[4];
    auto load_phase = [&](int ph) {
        #pragma unroll
        for (int i = 0; i < 4; i++) {
            const int idx = tid + 256*i;
            px[i] = *(const float4*)(x + (size_t)(m0+(idx>>4))*DIM + ph*64 + (idx&15)*4);
        }
        #pragma unroll
        for (int i = 0; i < 4; i++) {
            const int idx = tid + 256*i;
            pwh[i] = *(const uint4*)(Wth + (size_t)(n0+(idx>>3))*DIM + ph*64 + (idx&7)*8);
            pwl[i] = *(const uint4*)(Wtl + (size_t)(n0+(idx>>3))*DIM + ph*64 + (idx&7)*8);
        }
    };
    load_phase(0);

    #pragma unroll
    for (int ph = 0; ph < 2; ph++) {
        __syncthreads();
        #pragma unroll
        for (int i = 0; i < 4; i++) {
            const int idx = tid + 256*i;
            const int r = idx >> 4, f4 = idx & 15;
            const float4 v = px[i];
            f16_t h0=(f16_t)v.x, h1=(f16_t)v.y, h2=(f16_t)v.z, h3=(f16_t)v.w;
            *(f16x4*)(sXh + r*LDXX + f4*4) = (f16x4){h0,h1,h2,h3};
            *(f16x4*)(sXl + r*LDXX + f4*4) =
                (f16x4){(f16_t)(v.x-(float)h0),(f16_t)(v.y-(float)h1),
                        (f16_t)(v.z-(float)h2),(f16_t)(v.w-(float)h3)};
        }
        #pragma unroll
        for (int i = 0; i < 4; i++) {
            const int idx = tid + 256*i;
            const int n = idx >> 3, g = idx & 7;
            const f16x8 wh = __builtin_bit_cast(f16x8, pwh[i]);
            const f16x8 wl = __builtin_bit_cast(f16x8, pwl[i]);
            *(f16x4*)(sWh + n*LDW + g*8    ) = __builtin_shufflevector(wh, wh, 0,1,2,3);
            *(f16x4*)(sWh + n*LDW + g*8 + 4) = __builtin_shufflevector(wh, wh, 4,5,6,7);
            *(f16x4*)(sWl + n*LDW + g*8    ) = __builtin_shufflevector(wl, wl, 0,1,2,3);
            *(f16x4*)(sWl + n*LDW + g*8 + 4) = __builtin_shufflevector(wl, wl, 4,5,6,7);
        }
        if (ph == 0) load_phase(1);   // prefetch phase-1 during phase-0 compute
        __syncthreads();

        f16x8 ah[2], al[2];
        #pragma unroll
        for (int ks = 0; ks < 2; ks++) {
            ah[ks] = *(const f16x8*)(sXh + (wave*16+ln)*LDXX + quad*8 + ks*32);
            al[ks] = *(const f16x8*)(sXl + (wave*16+ln)*LDXX + quad*8 + ks*32);
        }
        #pragma unroll
        for (int nb = 0; nb < 8; nb++) {
            #pragma unroll
            for (int ks = 0; ks < 2; ks++) {
                const f16_t* wb = sWh + (nb*16+ln)*LDW + quad*8 + ks*32;
                const f16x4 b0 = *(const f16x4*)(wb);
                const f16x4 b1 = *(const f16x4*)(wb + 4);
                const f16x8 bh = __builtin_shufflevector(b0, b1, 0,1,2,3,4,5,6,7);
                const f16_t* wc = sWl + (nb*16+ln)*LDW + quad*8 + ks*32;
                const f16x4 c0 = *(const f16x4*)(wc);
                const f16x4 c1 = *(const f16x4*)(wc + 4);
                const f16x8 bl = __builtin_shufflevector(c0, c1, 0,1,2,3,4,5,6,7);
                acc[nb] = __builtin_amdgcn_mfma_f32_16x16x32_f16(ah[ks], bh, acc[nb], 0,0,0);
                acc[nb] = __builtin_amdgcn_mfma_f32_16x16x32_f16(al[ks], bh, acc[nb], 0,0,0);
                acc[nb] = __builtin_amdgcn_mfma_f32_16x16x32_f16(ah[ks], bl, acc[nb], 0,0,0);
            }
        }
    }

    __syncthreads();   // done with staging LDS

    if (nt != 2) {
        // ---- Q/K epilogue: swizzled LDS transpose -> coalesced b128 stores ----
        const float scale = (nt == 0) ? QSCALE : 1.0f;
        f16_t* dsth = (nt == 0) ? Qh : Kh;
        f16_t* sH = smem;             // 64 x LDE = 17408 B
        #pragma unroll
        for (int nb = 0; nb < 8; nb++)
            #pragma unroll
            for (int r = 0; r < 4; r++) {
                const int row  = wave*16 + quad*4 + r;
                const int colp = (nb*16 + ln) ^ (quad << 4);
                sH[row*LDE + colp] = (f16_t)(acc[nb][r] * scale);
            }
        __syncthreads();
        #pragma unroll
        for (int jj = 0; jj < 4; jj++) {
            const int c    = tid + 256*jj;
            const int row  = c >> 4;
            const int col  = (c & 15) * 8;
            const int colp = col ^ (((row >> 2) & 3) << 4);
            *(uint4*)(dsth + (size_t)(m0 + row)*DIM + col) =
                *(const uint4*)(sH + row*LDE + colp);
        }
    } else {
        // ---- V epilogue: transpose to Vt[b][d][s] ----
        f16_t* svt = smem;                  // 128 x LDXX = 18432 B
        const int rowl = wave*16 + quad*4;
        #pragma unroll
        for (int nb = 0; nb < 8; nb++)
            for (int r = 0; r < 4; r++)
                svt[(nb*16+ln)*LDXX + rowl + r] = (f16_t)acc[nb][r];
        __syncthreads();
        const int bb = m0 >> 12, sloc = m0 & (SEQ-1);
        const int d = tid >> 1, half = tid & 1;
        #pragma unroll
        for (int q = 0; q < 4; q++) {
            *(uint4*)(Vt + ((size_t)bb*DIM + d)*SEQ + sloc + half*32 + q*8) =
                *(const uint4*)(svt + d*LDXX + half*32 + q*8);
        }
    }
}

// ---------------------------------------------------------------------------
// Kernel 2: fused flash attention, S^T formulation on 32x32x16 MFMA.
// Round 13: (a) V LDS columns stored with bits 2<->3 of s swapped so the
// PV A-fragment is CONTIGUOUS -> single ds_read_b128 (was 2x b64); the swap
// matches the MFMA C-layout k-permutation of the P B-frag exactly, so math
// is bit-identical. (b) k+1 register prefetch issued after the S^T MFMAs
// (fits at (256,3): ~116 regs; the R8 spill was the (256,4)=128 cap).
// In-kernel split-K merge (round 10) REGRESSED 3.6x -- keep separate combine.
// ---------------------------------------------------------------------------
#define LDK 136   // K rows 16B-aligned -> single ds_read_b128 frags
#define LDV 72    // V^T rows 16B-aligned -> single ds_read_b128 frags
#define LDO 132

__global__ __launch_bounds__(256, 3) void flash_kernel(
    const f16_t* __restrict__ Qh, const f16_t* __restrict__ Kh,
    const f16_t* __restrict__ Vt,
    f16_t* __restrict__ Opart, float2* __restrict__ mlbuf)
{
    __shared__ __align__(16) f16_t smem[64*LDK + 128*LDV]; // 35840 B
    f16_t* sK = smem;
    f16_t* sV = smem + 64*LDK;

    const int tid  = threadIdx.x;
    const int wave = tid >> 6;
    const int lane = tid & 63;
    const int l31  = lane & 31;
    const int h    = lane >> 5;

    const int grp = blockIdx.x & 15;          // b*4+sp -> XCD-local K/V slice
    const int b   = grp >> 2;
    const int sp  = grp & 3;
    const int qt  = blockIdx.x >> 4;          // 0..31
    const int q0  = qt*128 + wave*32;

    // Q B-frags: lane holds Q[q = q0+l31][d = ks*16 + h*8 + j], j=0..7
    f16x8 qf[8];
    {
        const f16_t* gq = Qh + ((size_t)b*SEQ + q0 + l31)*DIM + h*8;
        #pragma unroll
        for (int ks = 0; ks < 8; ks++)
            qf[ks] = *(const f16x8*)(gq + ks*16);
    }

    f32x16 oacc[4];
    #pragma unroll
    for (int mb = 0; mb < 4; mb++)
        #pragma unroll
        for (int r = 0; r < 16; r++) oacc[mb][r] = 0.f;
    float mrun = -__builtin_inff(), lrun = 0.f;

    // staging coords (K: 64x128 tile b128; V: 128x64 tile 2xb64 swizzled)
    const int kr = tid >> 4;
    const int kc = (tid & 15) * 8;
    const int vd = tid >> 3;
    const int vj = (tid & 7) * 8;
    // swizzled store columns: s = vj + e; store col = swap(bit2,bit3)(s)
    const int vclo = (vj & 0x30) + ((vj & 8) >> 1);   // e = 0..3
    const int vchi = vclo + 8;                        // e = 4..7

    const f16_t* gK = Kh + (size_t)b*SEQ*DIM;
    const f16_t* gV = Vt + (size_t)b*DIM*SEQ;

    const int kt0 = sp*16, kend = sp*16 + 16;

    float4 pk[4], pv[4];
    auto load_tile = [&](int kt) {
        const f16_t* gk = gK + (size_t)kt*64*DIM;
        const f16_t* gv = gV + kt*64;
        #pragma unroll
        for (int p = 0; p < 4; p++)
            pk[p] = *(const float4*)(gk + (kr + 16*p)*DIM + kc);
        #pragma unroll
        for (int p = 0; p < 4; p++)
            pv[p] = *(const float4*)(gv + (size_t)(vd + 32*p)*SEQ + vj);
    };
    load_tile(kt0);   // prime the pipeline

    for (int kt = kt0; kt < kend; kt++) {
        __syncthreads();   // all waves done reading previous tile
        #pragma unroll
        for (int p = 0; p < 4; p++)
            *(uint4*)(sK + (kr+16*p)*LDK + kc) = __builtin_bit_cast(uint4, pk[p]);
        #pragma unroll
        for (int p = 0; p < 4; p++) {
            const f16x8 w = __builtin_bit_cast(f16x8, pv[p]);
            *(f16x4*)(sV + (vd+32*p)*LDV + vclo) = __builtin_shufflevector(w, w, 0,1,2,3);
            *(f16x4*)(sV + (vd+32*p)*LDV + vchi) = __builtin_shufflevector(w, w, 4,5,6,7);
        }
        __syncthreads();

        // ---- S^T = K Q^T : 2 s-blocks x 8 k-steps, b128 A-frags ----
        f32x16 sacc[2];
        #pragma unroll
        for (int sb = 0; sb < 2; sb++)
            #pragma unroll
            for (int r = 0; r < 16; r++) sacc[sb][r] = 0.f;
        #pragma unroll
        for (int ks = 0; ks < 8; ks++) {
            #pragma unroll
            for (int sb = 0; sb < 2; sb++) {
                const f16x8 af = *(const f16x8*)(sK + (sb*32 + l31)*LDK + ks*16 + h*8);
                sacc[sb] = __builtin_amdgcn_mfma_f32_32x32x16_f16(af, qf[ks], sacc[sb], 0,0,0);
            }
        }

        // prefetch next tile into registers; latency hides under softmax+PV
        if (kt + 1 < kend) load_tile(kt + 1);

        // ---- online softmax: per-lane state (q = l31) ----
        float mx = sacc[0][0];
        #pragma unroll
        for (int sb = 0; sb < 2; sb++)
            #pragma unroll
            for (int r = 0; r < 16; r++) mx = fmaxf(mx, sacc[sb][r]);
        mx = fmaxf(mx, __shfl_xor(mx, 32, 64));
        const float mnew = fmaxf(mrun, mx);

        if (__any(mnew > mrun)) {      // wave-uniform: some q-row's max advanced
            const float alpha = __builtin_amdgcn_exp2f(mrun - mnew);
            lrun *= alpha;
            #pragma unroll
            for (int mb = 0; mb < 4; mb++)
                #pragma unroll
                for (int r = 0; r < 16; r++) oacc[mb][r] *= alpha;
            mrun = mnew;
        }

        // exp + packed f32->f16 (v_cvt_pkrtz)
        union PBuf { f16x2 p2[8]; f16x8 v8[2]; } pbf[2];
        float rs = 0.f;
        #pragma unroll
        for (int sb = 0; sb < 2; sb++)
            #pragma unroll
            for (int r2 = 0; r2 < 8; r2++) {
                const float e0 = __builtin_amdgcn_exp2f(sacc[sb][2*r2]   - mnew);
                const float e1 = __builtin_amdgcn_exp2f(sacc[sb][2*r2+1] - mnew);
                rs += e0 + e1;
                pbf[sb].p2[r2] = __builtin_bit_cast(f16x2,
                    __builtin_amdgcn_cvt_pkrtz(e0, e1));
            }
        rs += __shfl_xor(rs, 32, 64);
        lrun += rs;

        // ---- O^T += V^T P^T : P B-frag = sacc regs; V A-frag single b128 ----
        #pragma unroll
        for (int t = 0; t < 4; t++) {
            const f16x8 pb = pbf[t>>1].v8[t&1];
            #pragma unroll
            for (int mb = 0; mb < 4; mb++) {
                const f16x8 af = *(const f16x8*)(sV + (mb*32 + l31)*LDV + t*16 + h*8);
                oacc[mb] = __builtin_amdgcn_mfma_f32_32x32x16_f16(af, pb, oacc[mb], 0,0,0);
            }
        }
    }

    // ---- epilogue: O^T -> LDS transpose (wave-local) -> coalesced stores ----
    __syncthreads();   // other waves done reading sK/sV
    const float invl = 1.f / lrun;
    f16_t* sOw = smem + wave*32*LDO;   // 32 q-rows x 128 d
    #pragma unroll
    for (int mb = 0; mb < 4; mb++)
        #pragma unroll
        for (int rp = 0; rp < 8; rp++) {
            const int r0 = rp*2;
            const int d  = mb*32 + (r0 & 3) + 8*(r0 >> 2) + 4*h;
            union { f16_t f[2]; unsigned u; } pkv;
            pkv.f[0] = (f16_t)(oacc[mb][r0]   * invl);
            pkv.f[1] = (f16_t)(oacc[mb][r0+1] * invl);
            *(unsigned*)(sOw + l31*LDO + d) = pkv.u;
        }
    __asm__ volatile("s_waitcnt lgkmcnt(0)" ::: "memory");  // wave-local round-trip

    const size_t gb = ((size_t)sp*NROW + (size_t)b*SEQ + q0)*DIM;
    #pragma unroll
    for (int jj = 0; jj < 8; jj++) {
        const int c  = lane + 64*jj;
        const int q  = c >> 4;
        const int dc = (c & 15)*8;
        union { f16x4 v[2]; uint4 u; } o;
        o.v[0] = *(const f16x4*)(sOw + q*LDO + dc);
        o.v[1] = *(const f16x4*)(sOw + q*LDO + dc + 4);
        *(uint4*)(Opart + gb + (size_t)q*DIM + dc) = o.u;
    }
    if (h == 0)
        mlbuf[sp*NROW + b*SEQ + q0 + l31] = make_float2(mrun, lrun);
}

// ---------------------------------------------------------------------------
// Kernel 3: combine the KV-split partials.
// ---------------------------------------------------------------------------
__global__ __launch_bounds__(256) void combine_kernel(
    const f16_t* __restrict__ Opart, const float2* __restrict__ mlbuf,
    float* __restrict__ out)
{
    const int idx = blockIdx.x*256 + threadIdx.x;
    const int row = idx >> 4;
    const int d0  = (idx & 15) * 8;

    float m[NSPLIT], l[NSPLIT];
    #pragma unroll
    for (int s = 0; s < NSPLIT; s++) {
        const float2 v = mlbuf[s*NROW + row];
        m[s] = v.x; l[s] = v.y;
    }
    float M = m[0];
    #pragma unroll
    for (int s = 1; s < NSPLIT; s++) M = fmaxf(M, m[s]);
    float w[NSPLIT], denom = 0.f;
    #pragma unroll
    for (int s = 0; s < NSPLIT; s++) {
        w[s] = l[s] * __builtin_amdgcn_exp2f(m[s] - M);
        denom += w[s];
    }
    const float inv = 1.f / denom;

    float o[8] = {0,0,0,0,0,0,0,0};
    #pragma unroll
    for (int s = 0; s < NSPLIT; s++) {
        const f16x8 v = *(const f16x8*)(Opart + ((size_t)s*NROW + row)*DIM + d0);
        const float ws = w[s] * inv;
        #pragma unroll
        for (int j = 0; j < 8; j++) o[j] += ws * (float)v[j];
    }
    float* ob = out + (size_t)row*DIM + d0;
    *(float4*)(ob)     = make_float4(o[0], o[1], o[2], o[3]);
    *(float4*)(ob + 4) = make_float4(o[4], o[5], o[6], o[7]);
}

// ---------------------------------------------------------------------------
extern "C" void kernel_launch(void* const* d_in, const int* in_sizes, int n_in,
                              void* d_out, int out_size, void* d_ws, size_t ws_size,
                              hipStream_t stream) {
    const float* x  = (const float*)d_in[0];
    // d_in[1] = token_attention_masks (unused: reference softmaxes UNMASKED scores)
    const float* wq = (const float*)d_in[2];
    const float* wk = (const float*)d_in[3];
    const float* wv = (const float*)d_in[4];

    f16_t* ws = (f16_t*)d_ws;
    f16_t* Qh    = ws;                                    // NROW*DIM each
    f16_t* Kh    = Qh  + (size_t)NROW*DIM;
    f16_t* Vt    = Kh  + (size_t)NROW*DIM;                // [B][D][S]
    f16_t* Wth   = Vt  + (size_t)NROW*DIM;                // NW*DIM each
    f16_t* Wtl   = Wth + (size_t)NW*DIM;
    f16_t* Opart = Wtl + (size_t)NW*DIM;                  // NSPLIT x NROW x DIM
    float2* mlbuf = (float2*)(Opart + (size_t)NSPLIT*NROW*DIM);

    wsplit_kernel <<<NW*DIM/256,            256, 0, stream>>>(wq, wk, wv, Wth, Wtl);
    proj_kernel   <<<(NROW/64)*3,           256, 0, stream>>>(x, Wth, Wtl, Qh, Kh, Vt);
    flash_kernel  <<<BATCH*(SEQ/128)*NSPLIT,256, 0, stream>>>(Qh, Kh, Vt, Opart, mlbuf);
    combine_kernel<<<NROW*DIM/8/256,        256, 0, stream>>>(Opart, mlbuf, (float*)d_out);
}

// Round 14
// 122.444 us; speedup vs baseline: 1.1222x; 1.1222x over previous
//
#include <hip/hip_runtime.h>
#include <math.h>

#define BATCH  4
#define SEQ    4096
#define DIM    128
#define NROW   (BATCH*SEQ)
#define NSPLIT 4
#define NW     384   // concatenated W cols (q|k|v)

typedef _Float16 f16_t;
typedef _Float16 f16x2  __attribute__((ext_vector_type(2)));
typedef _Float16 f16x4  __attribute__((ext_vector_type(4)));
typedef _Float16 f16x8  __attribute__((ext_vector_type(8)));
typedef _Float16 f16x16 __attribute__((ext_vector_type(16)));
typedef float    f32x4  __attribute__((ext_vector_type(4)));
typedef float    f32x16 __attribute__((ext_vector_type(16)));

// softmax scale 1/sqrt(128) and log2(e) folded into Q
#define QSCALE ((float)(1.4426950408889634 / 11.313708498984761))

// ---------------------------------------------------------------------------
// Kernel 0: transpose+hi/lo-split W once: Wt[n][k] = W[k][n] as f16 h/l.
// ---------------------------------------------------------------------------
__global__ __launch_bounds__(256) void wsplit_kernel(
    const float* __restrict__ wq, const float* __restrict__ wk,
    const float* __restrict__ wv,
    f16_t* __restrict__ Wth, f16_t* __restrict__ Wtl)
{
    const int idx = blockIdx.x*256 + threadIdx.x;   // 49152 = 384*128
    const int n = idx >> 7;
    const int k = idx & 127;
    const int mat = n >> 7, col = n & 127;
    const float* w = (mat == 0) ? wq : ((mat == 1) ? wk : wv);
    const float v = w[k*DIM + col];
    const f16_t h = (f16_t)v;
    Wth[idx] = h;
    Wtl[idx] = (f16_t)(v - (float)h);
}

// ---------------------------------------------------------------------------
// Kernel 1: QKV projection as MFMA GEMM (3-term compensated, fp32-accurate).
// LDS 53248 B (3 blocks/CU), phase-1 register prefetch.
// ---------------------------------------------------------------------------
#define LDXX 72   // X staging stride (144B, b128 frag reads)
#define LDW  68   // W staging stride (136B, 2xb64 frag reads)
#define LDE 136   // epilogue transpose stride

__global__ __launch_bounds__(256, 3) void proj_kernel(
    const float* __restrict__ x,
    const f16_t* __restrict__ Wth, const f16_t* __restrict__ Wtl,
    f16_t* __restrict__ Qh, f16_t* __restrict__ Kh, f16_t* __restrict__ Vt)
{
    __shared__ __align__(16) f16_t smem[(64+64)*LDXX + (128+128)*LDW]; // 53248 B
    f16_t* sXh = smem;
    f16_t* sXl = smem + 64*LDXX;
    f16_t* sWh = smem + 128*LDXX;
    f16_t* sWl = smem + 128*LDXX + 128*LDW;

    const int tid  = threadIdx.x;
    const int wave = tid >> 6;
    const int lane = tid & 63;
    const int quad = lane >> 4;
    const int ln   = lane & 15;

    const int nt = blockIdx.x % 3;          // 0=Q 1=K 2=V
    const int mb = blockIdx.x / 3;
    const int m0 = mb * 64;
    const int n0 = nt * 128;

    f32x4 acc[8];
    #pragma unroll
    for (int nb = 0; nb < 8; nb++)
        for (int r = 0; r < 4; r++) acc[nb][r] = 0.f;

    float4 px[4]; uint4 pwh[4], pwl[4];
    auto load_phase = [&](int ph) {
        #pragma unroll
        for (int i = 0; i < 4; i++) {
            const int idx = tid + 256*i;
            px[i] = *(const float4*)(x + (size_t)(m0+(idx>>4))*DIM + ph*64 + (idx&15)*4);
        }
        #pragma unroll
        for (int i = 0; i < 4; i++) {
            const int idx = tid + 256*i;
            pwh[i] = *(const uint4*)(Wth + (size_t)(n0+(idx>>3))*DIM + ph*64 + (idx&7)*8);
            pwl[i] = *(const uint4*)(Wtl + (size_t)(n0+(idx>>3))*DIM + ph*64 + (idx&7)*8);
        }
    };
    load_phase(0);

    #pragma unroll
    for (int ph = 0; ph < 2; ph++) {
        __syncthreads();
        #pragma unroll
        for (int i = 0; i < 4; i++) {
            const int idx = tid + 256*i;
            const int r = idx >> 4, f4 = idx & 15;
            const float4 v = px[i];
            f16_t h0=(f16_t)v.x, h1=(f16_t)v.y, h2=(f16_t)v.z, h3=(f16_t)v.w;
            *(f16x4*)(sXh + r*LDXX + f4*4) = (f16x4){h0,h1,h2,h3};
            *(f16x4*)(sXl + r*LDXX + f4*4) =
                (f16x4){(f16_t)(v.x-(float)h0),(f16_t)(v.y-(float)h1),
                        (f16_t)(v.z-(float)h2),(f16_t)(v.w-(float)h3)};
        }
        #pragma unroll
        for (int i = 0; i < 4; i++) {
            const int idx = tid + 256*i;
            const int n = idx >> 3, g = idx & 7;
            const f16x8 wh = __builtin_bit_cast(f16x8, pwh[i]);
            const f16x8 wl = __builtin_bit_cast(f16x8, pwl[i]);
            *(f16x4*)(sWh + n*LDW + g*8    ) = __builtin_shufflevector(wh, wh, 0,1,2,3);
            *(f16x4*)(sWh + n*LDW + g*8 + 4) = __builtin_shufflevector(wh, wh, 4,5,6,7);
            *(f16x4*)(sWl + n*LDW + g*8    ) = __builtin_shufflevector(wl, wl, 0,1,2,3);
            *(f16x4*)(sWl + n*LDW + g*8 + 4) = __builtin_shufflevector(wl, wl, 4,5,6,7);
        }
        if (ph == 0) load_phase(1);   // prefetch phase-1 during phase-0 compute
        __syncthreads();

        f16x8 ah[2], al[2];
        #pragma unroll
        for (int ks = 0; ks < 2; ks++) {
            ah[ks] = *(const f16x8*)(sXh + (wave*16+ln)*LDXX + quad*8 + ks*32);
            al[ks] = *(const f16x8*)(sXl + (wave*16+ln)*LDXX + quad*8 + ks*32);
        }
        #pragma unroll
        for (int nb = 0; nb < 8; nb++) {
            #pragma unroll
            for (int ks = 0; ks < 2; ks++) {
                const f16_t* wb = sWh + (nb*16+ln)*LDW + quad*8 + ks*32;
                const f16x4 b0 = *(const f16x4*)(wb);
                const f16x4 b1 = *(const f16x4*)(wb + 4);
                const f16x8 bh = __builtin_shufflevector(b0, b1, 0,1,2,3,4,5,6,7);
                const f16_t* wc = sWl + (nb*16+ln)*LDW + quad*8 + ks*32;
                const f16x4 c0 = *(const f16x4*)(wc);
                const f16x4 c1 = *(const f16x4*)(wc + 4);
                const f16x8 bl = __builtin_shufflevector(c0, c1, 0,1,2,3,4,5,6,7);
                acc[nb] = __builtin_amdgcn_mfma_f32_16x16x32_f16(ah[ks], bh, acc[nb], 0,0,0);
                acc[nb] = __builtin_amdgcn_mfma_f32_16x16x32_f16(al[ks], bh, acc[nb], 0,0,0);
                acc[nb] = __builtin_amdgcn_mfma_f32_16x16x32_f16(ah[ks], bl, acc[nb], 0,0,0);
            }
        }
    }

    __syncthreads();   // done with staging LDS

    if (nt != 2) {
        // ---- Q/K epilogue: swizzled LDS transpose -> coalesced b128 stores ----
        const float scale = (nt == 0) ? QSCALE : 1.0f;
        f16_t* dsth = (nt == 0) ? Qh : Kh;
        f16_t* sH = smem;             // 64 x LDE = 17408 B
        #pragma unroll
        for (int nb = 0; nb < 8; nb++)
            #pragma unroll
            for (int r = 0; r < 4; r++) {
                const int row  = wave*16 + quad*4 + r;
                const int colp = (nb*16 + ln) ^ (quad << 4);
                sH[row*LDE + colp] = (f16_t)(acc[nb][r] * scale);
            }
        __syncthreads();
        #pragma unroll
        for (int jj = 0; jj < 4; jj++) {
            const int c    = tid + 256*jj;
            const int row  = c >> 4;
            const int col  = (c & 15) * 8;
            const int colp = col ^ (((row >> 2) & 3) << 4);
            *(uint4*)(dsth + (size_t)(m0 + row)*DIM + col) =
                *(const uint4*)(sH + row*LDE + colp);
        }
    } else {
        // ---- V epilogue: transpose to Vt[b][d][s] ----
        f16_t* svt = smem;                  // 128 x LDXX = 18432 B
        const int rowl = wave*16 + quad*4;
        #pragma unroll
        for (int nb = 0; nb < 8; nb++)
            for (int r = 0; r < 4; r++)
                svt[(nb*16+ln)*LDXX + rowl + r] = (f16_t)acc[nb][r];
        __syncthreads();
        const int bb = m0 >> 12, sloc = m0 & (SEQ-1);
        const int d = tid >> 1, half = tid & 1;
        #pragma unroll
        for (int q = 0; q < 4; q++) {
            *(uint4*)(Vt + ((size_t)bb*DIM + d)*SEQ + sloc + half*32 + q*8) =
                *(const uint4*)(svt + d*LDXX + half*32 + q*8);
        }
    }
}

// ---------------------------------------------------------------------------
// Kernel 2: fused flash attention, S^T formulation on 32x32x16 MFMA.
// EXACT round-12 core (45.3 us proven: loads at loop top so pk/pv die at the
// barrier -- R13's post-MFMA prefetch stretched their lifetime across softmax
// and spilled; R13's V-b128 read at LDV=72 was 4-way bank-aliased vs free
// 2-way b64 at 68 -- both reverted) + ONE new change: wave-uniform
// negligible-tile skip. Tiles whose max logit is >25 bits below the running
// max contribute < 2^-25 relative mass -> skip exp + PV MFMAs + V reads.
// No barrier sits in the skipped region, so per-wave `continue` is sync-safe.
// ---------------------------------------------------------------------------
#define LDK 136   // K rows 16B-aligned -> single ds_read_b128 frags
#define LDV 68    // V^T rows: b64 reads 2-way (free)
#define LDO 132

__global__ __launch_bounds__(256, 3) void flash_kernel(
    const f16_t* __restrict__ Qh, const f16_t* __restrict__ Kh,
    const f16_t* __restrict__ Vt,
    f16_t* __restrict__ Opart, float2* __restrict__ mlbuf)
{
    __shared__ __align__(16) f16_t smem[64*LDK + 128*LDV]; // 34816 B
    f16_t* sK = smem;
    f16_t* sV = smem + 64*LDK;

    const int tid  = threadIdx.x;
    const int wave = tid >> 6;
    const int lane = tid & 63;
    const int l31  = lane & 31;
    const int h    = lane >> 5;

    const int grp = blockIdx.x & 15;          // b*4+sp -> XCD-local K/V slice
    const int b   = grp >> 2;
    const int sp  = grp & 3;
    const int qt  = blockIdx.x >> 4;          // 0..31
    const int q0  = qt*128 + wave*32;

    // Q B-frags: lane holds Q[q = q0+l31][d = ks*16 + h*8 + j], j=0..7
    f16x8 qf[8];
    {
        const f16_t* gq = Qh + ((size_t)b*SEQ + q0 + l31)*DIM + h*8;
        #pragma unroll
        for (int ks = 0; ks < 8; ks++)
            qf[ks] = *(const f16x8*)(gq + ks*16);
    }

    f32x16 oacc[4];
    #pragma unroll
    for (int mb = 0; mb < 4; mb++)
        #pragma unroll
        for (int r = 0; r < 16; r++) oacc[mb][r] = 0.f;
    float mrun = -__builtin_inff(), lrun = 0.f;

    // staging coords (K: 64x128 tile b128; V: 128x64 tile 2xb64)
    const int kr = tid >> 4;
    const int kc = (tid & 15) * 8;
    const int vd = tid >> 3;
    const int vj = (tid & 7) * 8;

    const f16_t* gK = Kh + (size_t)b*SEQ*DIM;
    const f16_t* gV = Vt + (size_t)b*DIM*SEQ;

    for (int kt = sp*16; kt < sp*16 + 16; kt++) {
        float4 pk[4], pv[4];
        {   // issue global loads before the barrier (latency overlap;
            // pk/pv die at the stores right after -> no register pressure)
            const f16_t* gk = gK + (size_t)kt*64*DIM;
            const f16_t* gv = gV + kt*64;
            #pragma unroll
            for (int p = 0; p < 4; p++)
                pk[p] = *(const float4*)(gk + (kr + 16*p)*DIM + kc);
            #pragma unroll
            for (int p = 0; p < 4; p++)
                pv[p] = *(const float4*)(gv + (size_t)(vd + 32*p)*SEQ + vj);
        }
        __syncthreads();   // all waves done reading previous tile
        #pragma unroll
        for (int p = 0; p < 4; p++)
            *(uint4*)(sK + (kr+16*p)*LDK + kc) = __builtin_bit_cast(uint4, pk[p]);
        #pragma unroll
        for (int p = 0; p < 4; p++) {
            const f16x8 w = __builtin_bit_cast(f16x8, pv[p]);
            *(f16x4*)(sV + (vd+32*p)*LDV + vj    ) = __builtin_shufflevector(w, w, 0,1,2,3);
            *(f16x4*)(sV + (vd+32*p)*LDV + vj + 4) = __builtin_shufflevector(w, w, 4,5,6,7);
        }
        __syncthreads();

        // ---- S^T = K Q^T : 2 s-blocks x 8 k-steps, b128 A-frags ----
        f32x16 sacc[2];
        #pragma unroll
        for (int sb = 0; sb < 2; sb++)
            #pragma unroll
            for (int r = 0; r < 16; r++) sacc[sb][r] = 0.f;
        #pragma unroll
        for (int ks = 0; ks < 8; ks++) {
            #pragma unroll
            for (int sb = 0; sb < 2; sb++) {
                const f16x8 af = *(const f16x8*)(sK + (sb*32 + l31)*LDK + ks*16 + h*8);
                sacc[sb] = __builtin_amdgcn_mfma_f32_32x32x16_f16(af, qf[ks], sacc[sb], 0,0,0);
            }
        }

        // ---- online softmax: per-lane state (q = l31) ----
        float mx = sacc[0][0];
        #pragma unroll
        for (int sb = 0; sb < 2; sb++)
            #pragma unroll
            for (int r = 0; r < 16; r++) mx = fmaxf(mx, sacc[sb][r]);
        mx = fmaxf(mx, __shfl_xor(mx, 32, 64));
        const float mnew = fmaxf(mrun, mx);

        if (__any(mnew > mrun)) {      // wave-uniform: some q-row's max advanced
            const float alpha = __builtin_amdgcn_exp2f(mrun - mnew);
            lrun *= alpha;
            #pragma unroll
            for (int mb = 0; mb < 4; mb++)
                #pragma unroll
                for (int r = 0; r < 16; r++) oacc[mb][r] *= alpha;
            mrun = mnew;
        }

        // ---- negligible-tile skip: whole tile < 2^-25 of running mass ----
        if (__all(mx < mrun - 25.f)) continue;   // no barrier skipped

        // exp + packed f32->f16 (v_cvt_pkrtz)
        union PBuf { f16x2 p2[8]; f16x8 v8[2]; } pbf[2];
        float rs = 0.f;
        #pragma unroll
        for (int sb = 0; sb < 2; sb++)
            #pragma unroll
            for (int r2 = 0; r2 < 8; r2++) {
                const float e0 = __builtin_amdgcn_exp2f(sacc[sb][2*r2]   - mnew);
                const float e1 = __builtin_amdgcn_exp2f(sacc[sb][2*r2+1] - mnew);
                rs += e0 + e1;
                pbf[sb].p2[r2] = __builtin_bit_cast(f16x2,
                    __builtin_amdgcn_cvt_pkrtz(e0, e1));
            }
        rs += __shfl_xor(rs, 32, 64);
        lrun += rs;

        // ---- O^T += V^T P^T : P B-frag = sacc regs directly ----
        #pragma unroll
        for (int t = 0; t < 4; t++) {
            const f16x8 pb = pbf[t>>1].v8[t&1];
            #pragma unroll
            for (int mb = 0; mb < 4; mb++) {
                const f16_t* va = sV + (mb*32 + l31)*LDV + t*16 + h*4;
                const f16x4 a0 = *(const f16x4*)(va);
                const f16x4 a1 = *(const f16x4*)(va + 8);
                const f16x8 af = __builtin_shufflevector(a0, a1, 0,1,2,3,4,5,6,7);
                oacc[mb] = __builtin_amdgcn_mfma_f32_32x32x16_f16(af, pb, oacc[mb], 0,0,0);
            }
        }
    }

    // ---- epilogue: O^T -> LDS transpose (wave-local) -> coalesced stores ----
    __syncthreads();   // other waves done reading sK/sV
    const float invl = 1.f / lrun;
    f16_t* sOw = smem + wave*32*LDO;   // 32 q-rows x 128 d
    #pragma unroll
    for (int mb = 0; mb < 4; mb++)
        #pragma unroll
        for (int rp = 0; rp < 8; rp++) {
            const int r0 = rp*2;
            const int d  = mb*32 + (r0 & 3) + 8*(r0 >> 2) + 4*h;
            union { f16_t f[2]; unsigned u; } pkv;
            pkv.f[0] = (f16_t)(oacc[mb][r0]   * invl);
            pkv.f[1] = (f16_t)(oacc[mb][r0+1] * invl);
            *(unsigned*)(sOw + l31*LDO + d) = pkv.u;
        }
    __asm__ volatile("s_waitcnt lgkmcnt(0)" ::: "memory");  // wave-local round-trip

    const size_t gb = ((size_t)sp*NROW + (size_t)b*SEQ + q0)*DIM;
    #pragma unroll
    for (int jj = 0; jj < 8; jj++) {
        const int c  = lane + 64*jj;
        const int q  = c >> 4;
        const int dc = (c & 15)*8;
        union { f16x4 v[2]; uint4 u; } o;
        o.v[0] = *(const f16x4*)(sOw + q*LDO + dc);
        o.v[1] = *(const f16x4*)(sOw + q*LDO + dc + 4);
        *(uint4*)(Opart + gb + (size_t)q*DIM + dc) = o.u;
    }
    if (h == 0)
        mlbuf[sp*NROW + b*SEQ + q0 + l31] = make_float2(mrun, lrun);
}

// ---------------------------------------------------------------------------
// Kernel 3: combine the KV-split partials.
// ---------------------------------------------------------------------------
__global__ __launch_bounds__(256) void combine_kernel(
    const f16_t* __restrict__ Opart, const float2* __restrict__ mlbuf,
    float* __restrict__ out)
{
    const int idx = blockIdx.x*256 + threadIdx.x;
    const int row = idx >> 4;
    const int d0  = (idx & 15) * 8;

    float m[NSPLIT], l[NSPLIT];
    #pragma unroll
    for (int s = 0; s < NSPLIT; s++) {
        const float2 v = mlbuf[s*NROW + row];
        m[s] = v.x; l[s] = v.y;
    }
    float M = m[0];
    #pragma unroll
    for (int s = 1; s < NSPLIT; s++) M = fmaxf(M, m[s]);
    float w[NSPLIT], denom = 0.f;
    #pragma unroll
    for (int s = 0; s < NSPLIT; s++) {
        w[s] = l[s] * __builtin_amdgcn_exp2f(m[s] - M);
        denom += w[s];
    }
    const float inv = 1.f / denom;

    float o[8] = {0,0,0,0,0,0,0,0};
    #pragma unroll
    for (int s = 0; s < NSPLIT; s++) {
        const f16x8 v = *(const f16x8*)(Opart + ((size_t)s*NROW + row)*DIM + d0);
        const float ws = w[s] * inv;
        #pragma unroll
        for (int j = 0; j < 8; j++) o[j] += ws * (float)v[j];
    }
    float* ob = out + (size_t)row*DIM + d0;
    *(float4*)(ob)     = make_float4(o[0], o[1], o[2], o[3]);
    *(float4*)(ob + 4) = make_float4(o[4], o[5], o[6], o[7]);
}

// ---------------------------------------------------------------------------
extern "C" void kernel_launch(void* const* d_in, const int* in_sizes, int n_in,
                              void* d_out, int out_size, void* d_ws, size_t ws_size,
                              hipStream_t stream) {
    const float* x  = (const float*)d_in[0];
    // d_in[1] = token_attention_masks (unused: reference softmaxes UNMASKED scores)
    const float* wq = (const float*)d_in[2];
    const float* wk = (const float*)d_in[3];
    const float* wv = (const float*)d_in[4];

    f16_t* ws = (f16_t*)d_ws;
    f16_t* Qh    = ws;                                    // NROW*DIM each
    f16_t* Kh    = Qh  + (size_t)NROW*DIM;
    f16_t* Vt    = Kh  + (size_t)NROW*DIM;                // [B][D][S]
    f16_t* Wth   = Vt  + (size_t)NROW*DIM;                // NW*DIM each
    f16_t* Wtl   = Wth + (size_t)NW*DIM;
    f16_t* Opart = Wtl + (size_t)NW*DIM;                  // NSPLIT x NROW x DIM
    float2* mlbuf = (float2*)(Opart + (size_t)NSPLIT*NROW*DIM);

    wsplit_kernel <<<NW*DIM/256,            256, 0, stream>>>(wq, wk, wv, Wth, Wtl);
    proj_kernel   <<<(NROW/64)*3,           256, 0, stream>>>(x, Wth, Wtl, Qh, Kh, Vt);
    flash_kernel  <<<BATCH*(SEQ/128)*NSPLIT,256, 0, stream>>>(Qh, Kh, Vt, Opart, mlbuf);
    combine_kernel<<<NROW*DIM/8/256,        256, 0, stream>>>(Opart, mlbuf, (float*)d_out);
}

// Round 15
// 120.795 us; speedup vs baseline: 1.1376x; 1.0137x over previous
//
#include <hip/hip_runtime.h>
#include <math.h>

#define BATCH  4
#define SEQ    4096
#define DIM    128
#define NROW   (BATCH*SEQ)
#define NSPLIT 4

typedef _Float16 f16_t;
typedef _Float16 f16x2  __attribute__((ext_vector_type(2)));
typedef _Float16 f16x4  __attribute__((ext_vector_type(4)));
typedef _Float16 f16x8  __attribute__((ext_vector_type(8)));
typedef _Float16 f16x16 __attribute__((ext_vector_type(16)));
typedef float    f32x4  __attribute__((ext_vector_type(4)));
typedef float    f32x16 __attribute__((ext_vector_type(16)));

// softmax scale 1/sqrt(128) and log2(e) folded into Q
#define QSCALE ((float)(1.4426950408889634 / 11.313708498984761))

// ---------------------------------------------------------------------------
// Kernel 1: QKV projection as MFMA GEMM (3-term compensated, fp32-accurate).
// Round 15: wsplit kernel FOLDED IN -- each block loads its W slice directly
// from fp32 (coalesced along n, L2-resident), converts to f16 h/l in regs,
// and writes the k-packed transpose to LDS (same 16 b64 DS writes/phase as
// the old pre-split load). One fewer dispatch; Wth/Wtl buffers deleted.
// ---------------------------------------------------------------------------
#define LDXX 72   // X staging stride (144B, b128 frag reads)
#define LDW  68   // W staging stride (136B, 2xb64 frag reads)
#define LDE 136   // epilogue transpose stride

__global__ __launch_bounds__(256, 3) void proj_kernel(
    const float* __restrict__ x,
    const float* __restrict__ wq, const float* __restrict__ wk,
    const float* __restrict__ wv,
    f16_t* __restrict__ Qh, f16_t* __restrict__ Kh, f16_t* __restrict__ Vt)
{
    __shared__ __align__(16) f16_t smem[(64+64)*LDXX + (128+128)*LDW]; // 53248 B
    f16_t* sXh = smem;
    f16_t* sXl = smem + 64*LDXX;
    f16_t* sWh = smem + 128*LDXX;
    f16_t* sWl = smem + 128*LDXX + 128*LDW;

    const int tid  = threadIdx.x;
    const int wave = tid >> 6;
    const int lane = tid & 63;
    const int quad = lane >> 4;
    const int ln   = lane & 15;

    const int nt = blockIdx.x % 3;          // 0=Q 1=K 2=V
    const int mb = blockIdx.x / 3;
    const int m0 = mb * 64;
    const float* __restrict__ w = (nt == 0) ? wq : ((nt == 1) ? wk : wv);

    // W staging coords: j-chunk: k0 rows (4 consecutive), n4*4 columns
    const int k0j[2] = { ((tid      ) >> 5) * 4, ((tid + 256) >> 5) * 4 };
    const int n4j[2] = { (tid       ) & 31,      (tid + 256) & 31       };

    f32x4 acc[8];
    #pragma unroll
    for (int nb = 0; nb < 8; nb++)
        for (int r = 0; r < 4; r++) acc[nb][r] = 0.f;

    float4 px[4];
    float  pw[2][16];
    auto load_phase = [&](int ph) {
        #pragma unroll
        for (int i = 0; i < 4; i++) {
            const int idx = tid + 256*i;
            px[i] = *(const float4*)(x + (size_t)(m0+(idx>>4))*DIM + ph*64 + (idx&15)*4);
        }
        #pragma unroll
        for (int j = 0; j < 2; j++)
            #pragma unroll
            for (int e = 0; e < 4; e++)
                *(float4*)&pw[j][e*4] =
                    *(const float4*)(w + (size_t)(ph*64 + k0j[j] + e)*DIM + n4j[j]*4);
    };
    load_phase(0);

    #pragma unroll
    for (int ph = 0; ph < 2; ph++) {
        __syncthreads();
        // stage X fp32 -> h/l
        #pragma unroll
        for (int i = 0; i < 4; i++) {
            const int idx = tid + 256*i;
            const int r = idx >> 4, f4 = idx & 15;
            const float4 v = px[i];
            f16_t h0=(f16_t)v.x, h1=(f16_t)v.y, h2=(f16_t)v.z, h3=(f16_t)v.w;
            *(f16x4*)(sXh + r*LDXX + f4*4) = (f16x4){h0,h1,h2,h3};
            *(f16x4*)(sXl + r*LDXX + f4*4) =
                (f16x4){(f16_t)(v.x-(float)h0),(f16_t)(v.y-(float)h1),
                        (f16_t)(v.z-(float)h2),(f16_t)(v.w-(float)h3)};
        }
        // stage W: convert + transpose in regs, k-packed b64 writes
        #pragma unroll
        for (int j = 0; j < 2; j++) {
            #pragma unroll
            for (int c = 0; c < 4; c++) {
                const int n = n4j[j]*4 + c;
                f16x4 hp, lp;
                #pragma unroll
                for (int e = 0; e < 4; e++) {
                    const float v = pw[j][e*4 + c];
                    const f16_t hh = (f16_t)v;
                    hp[e] = hh;
                    lp[e] = (f16_t)(v - (float)hh);
                }
                *(f16x4*)(sWh + n*LDW + k0j[j]) = hp;
                *(f16x4*)(sWl + n*LDW + k0j[j]) = lp;
            }
        }
        if (ph == 0) load_phase(1);   // prefetch phase-1 during phase-0 compute
        __syncthreads();

        f16x8 ah[2], al[2];
        #pragma unroll
        for (int ks = 0; ks < 2; ks++) {
            ah[ks] = *(const f16x8*)(sXh + (wave*16+ln)*LDXX + quad*8 + ks*32);
            al[ks] = *(const f16x8*)(sXl + (wave*16+ln)*LDXX + quad*8 + ks*32);
        }
        #pragma unroll
        for (int nb = 0; nb < 8; nb++) {
            #pragma unroll
            for (int ks = 0; ks < 2; ks++) {
                const f16_t* wb = sWh + (nb*16+ln)*LDW + quad*8 + ks*32;
                const f16x4 b0 = *(const f16x4*)(wb);
                const f16x4 b1 = *(const f16x4*)(wb + 4);
                const f16x8 bh = __builtin_shufflevector(b0, b1, 0,1,2,3,4,5,6,7);
                const f16_t* wc = sWl + (nb*16+ln)*LDW + quad*8 + ks*32;
                const f16x4 c0 = *(const f16x4*)(wc);
                const f16x4 c1 = *(const f16x4*)(wc + 4);
                const f16x8 bl = __builtin_shufflevector(c0, c1, 0,1,2,3,4,5,6,7);
                acc[nb] = __builtin_amdgcn_mfma_f32_16x16x32_f16(ah[ks], bh, acc[nb], 0,0,0);
                acc[nb] = __builtin_amdgcn_mfma_f32_16x16x32_f16(al[ks], bh, acc[nb], 0,0,0);
                acc[nb] = __builtin_amdgcn_mfma_f32_16x16x32_f16(ah[ks], bl, acc[nb], 0,0,0);
            }
        }
    }

    __syncthreads();   // done with staging LDS

    if (nt != 2) {
        // ---- Q/K epilogue: swizzled LDS transpose -> coalesced b128 stores ----
        const float scale = (nt == 0) ? QSCALE : 1.0f;
        f16_t* dsth = (nt == 0) ? Qh : Kh;
        f16_t* sH = smem;             // 64 x LDE = 17408 B
        #pragma unroll
        for (int nb = 0; nb < 8; nb++)
            #pragma unroll
            for (int r = 0; r < 4; r++) {
                const int row  = wave*16 + quad*4 + r;
                const int colp = (nb*16 + ln) ^ (quad << 4);
                sH[row*LDE + colp] = (f16_t)(acc[nb][r] * scale);
            }
        __syncthreads();
        #pragma unroll
        for (int jj = 0; jj < 4; jj++) {
            const int c    = tid + 256*jj;
            const int row  = c >> 4;
            const int col  = (c & 15) * 8;
            const int colp = col ^ (((row >> 2) & 3) << 4);
            *(uint4*)(dsth + (size_t)(m0 + row)*DIM + col) =
                *(const uint4*)(sH + row*LDE + colp);
        }
    } else {
        // ---- V epilogue: transpose to Vt[b][d][s] ----
        f16_t* svt = smem;                  // 128 x LDXX = 18432 B
        const int rowl = wave*16 + quad*4;
        #pragma unroll
        for (int nb = 0; nb < 8; nb++)
            for (int r = 0; r < 4; r++)
                svt[(nb*16+ln)*LDXX + rowl + r] = (f16_t)acc[nb][r];
        __syncthreads();
        const int bb = m0 >> 12, sloc = m0 & (SEQ-1);
        const int d = tid >> 1, half = tid & 1;
        #pragma unroll
        for (int q = 0; q < 4; q++) {
            *(uint4*)(Vt + ((size_t)bb*DIM + d)*SEQ + sloc + half*32 + q*8) =
                *(const uint4*)(svt + d*LDXX + half*32 + q*8);
        }
    }
}

// ---------------------------------------------------------------------------
// Kernel 2: fused flash attention, S^T formulation on 32x32x16 MFMA.
// Proven round-12/14 core (45 us): loads at loop top (pk/pv die at barrier),
// (256,3), raw v_exp_f32, v_cvt_pkrtz, alpha-skip, negligible-tile skip,
// b128 K frags, b64 V frags (LDV=68, 2-way-free).
// In-kernel split-K merge (R10) REGRESSED 3.6x -- keep separate combine.
// ---------------------------------------------------------------------------
#define LDK 136   // K rows 16B-aligned -> single ds_read_b128 frags
#define LDV 68    // V^T rows: b64 reads 2-way (free)
#define LDO 132

__global__ __launch_bounds__(256, 3) void flash_kernel(
    const f16_t* __restrict__ Qh, const f16_t* __restrict__ Kh,
    const f16_t* __restrict__ Vt,
    f16_t* __restrict__ Opart, float2* __restrict__ mlbuf)
{
    __shared__ __align__(16) f16_t smem[64*LDK + 128*LDV]; // 34816 B
    f16_t* sK = smem;
    f16_t* sV = smem + 64*LDK;

    const int tid  = threadIdx.x;
    const int wave = tid >> 6;
    const int lane = tid & 63;
    const int l31  = lane & 31;
    const int h    = lane >> 5;

    const int grp = blockIdx.x & 15;          // b*4+sp -> XCD-local K/V slice
    const int b   = grp >> 2;
    const int sp  = grp & 3;
    const int qt  = blockIdx.x >> 4;          // 0..31
    const int q0  = qt*128 + wave*32;

    // Q B-frags: lane holds Q[q = q0+l31][d = ks*16 + h*8 + j], j=0..7
    f16x8 qf[8];
    {
        const f16_t* gq = Qh + ((size_t)b*SEQ + q0 + l31)*DIM + h*8;
        #pragma unroll
        for (int ks = 0; ks < 8; ks++)
            qf[ks] = *(const f16x8*)(gq + ks*16);
    }

    f32x16 oacc[4];
    #pragma unroll
    for (int mb = 0; mb < 4; mb++)
        #pragma unroll
        for (int r = 0; r < 16; r++) oacc[mb][r] = 0.f;
    float mrun = -__builtin_inff(), lrun = 0.f;

    // staging coords (K: 64x128 tile b128; V: 128x64 tile 2xb64)
    const int kr = tid >> 4;
    const int kc = (tid & 15) * 8;
    const int vd = tid >> 3;
    const int vj = (tid & 7) * 8;

    const f16_t* gK = Kh + (size_t)b*SEQ*DIM;
    const f16_t* gV = Vt + (size_t)b*DIM*SEQ;

    for (int kt = sp*16; kt < sp*16 + 16; kt++) {
        float4 pk[4], pv[4];
        {   // issue global loads before the barrier (latency overlap;
            // pk/pv die at the stores right after -> no register pressure)
            const f16_t* gk = gK + (size_t)kt*64*DIM;
            const f16_t* gv = gV + kt*64;
            #pragma unroll
            for (int p = 0; p < 4; p++)
                pk[p] = *(const float4*)(gk + (kr + 16*p)*DIM + kc);
            #pragma unroll
            for (int p = 0; p < 4; p++)
                pv[p] = *(const float4*)(gv + (size_t)(vd + 32*p)*SEQ + vj);
        }
        __syncthreads();   // all waves done reading previous tile
        #pragma unroll
        for (int p = 0; p < 4; p++)
            *(uint4*)(sK + (kr+16*p)*LDK + kc) = __builtin_bit_cast(uint4, pk[p]);
        #pragma unroll
        for (int p = 0; p < 4; p++) {
            const f16x8 w = __builtin_bit_cast(f16x8, pv[p]);
            *(f16x4*)(sV + (vd+32*p)*LDV + vj    ) = __builtin_shufflevector(w, w, 0,1,2,3);
            *(f16x4*)(sV + (vd+32*p)*LDV + vj + 4) = __builtin_shufflevector(w, w, 4,5,6,7);
        }
        __syncthreads();

        // ---- S^T = K Q^T : 2 s-blocks x 8 k-steps, b128 A-frags ----
        f32x16 sacc[2];
        #pragma unroll
        for (int sb = 0; sb < 2; sb++)
            #pragma unroll
            for (int r = 0; r < 16; r++) sacc[sb][r] = 0.f;
        #pragma unroll
        for (int ks = 0; ks < 8; ks++) {
            #pragma unroll
            for (int sb = 0; sb < 2; sb++) {
                const f16x8 af = *(const f16x8*)(sK + (sb*32 + l31)*LDK + ks*16 + h*8);
                sacc[sb] = __builtin_amdgcn_mfma_f32_32x32x16_f16(af, qf[ks], sacc[sb], 0,0,0);
            }
        }

        // ---- online softmax: per-lane state (q = l31) ----
        float mx = sacc[0][0];
        #pragma unroll
        for (int sb = 0; sb < 2; sb++)
            #pragma unroll
            for (int r = 0; r < 16; r++) mx = fmaxf(mx, sacc[sb][r]);
        mx = fmaxf(mx, __shfl_xor(mx, 32, 64));
        const float mnew = fmaxf(mrun, mx);

        if (__any(mnew > mrun)) {      // wave-uniform: some q-row's max advanced
            const float alpha = __builtin_amdgcn_exp2f(mrun - mnew);
            lrun *= alpha;
            #pragma unroll
            for (int mb = 0; mb < 4; mb++)
                #pragma unroll
                for (int r = 0; r < 16; r++) oacc[mb][r] *= alpha;
            mrun = mnew;
        }

        // ---- negligible-tile skip: whole tile < 2^-25 of running mass ----
        if (__all(mx < mrun - 25.f)) continue;   // no barrier skipped

        // exp + packed f32->f16 (v_cvt_pkrtz)
        union PBuf { f16x2 p2[8]; f16x8 v8[2]; } pbf[2];
        float rs = 0.f;
        #pragma unroll
        for (int sb = 0; sb < 2; sb++)
            #pragma unroll
            for (int r2 = 0; r2 < 8; r2++) {
                const float e0 = __builtin_amdgcn_exp2f(sacc[sb][2*r2]   - mnew);
                const float e1 = __builtin_amdgcn_exp2f(sacc[sb][2*r2+1] - mnew);
                rs += e0 + e1;
                pbf[sb].p2[r2] = __builtin_bit_cast(f16x2,
                    __builtin_amdgcn_cvt_pkrtz(e0, e1));
            }
        rs += __shfl_xor(rs, 32, 64);
        lrun += rs;

        // ---- O^T += V^T P^T : P B-frag = sacc regs directly ----
        #pragma unroll
        for (int t = 0; t < 4; t++) {
            const f16x8 pb = pbf[t>>1].v8[t&1];
            #pragma unroll
            for (int mb = 0; mb < 4; mb++) {
                const f16_t* va = sV + (mb*32 + l31)*LDV + t*16 + h*4;
                const f16x4 a0 = *(const f16x4*)(va);
                const f16x4 a1 = *(const f16x4*)(va + 8);
                const f16x8 af = __builtin_shufflevector(a0, a1, 0,1,2,3,4,5,6,7);
                oacc[mb] = __builtin_amdgcn_mfma_f32_32x32x16_f16(af, pb, oacc[mb], 0,0,0);
            }
        }
    }

    // ---- epilogue: O^T -> LDS transpose (wave-local) -> coalesced stores ----
    __syncthreads();   // other waves done reading sK/sV
    const float invl = 1.f / lrun;
    f16_t* sOw = smem + wave*32*LDO;   // 32 q-rows x 128 d
    #pragma unroll
    for (int mb = 0; mb < 4; mb++)
        #pragma unroll
        for (int rp = 0; rp < 8; rp++) {
            const int r0 = rp*2;
            const int d  = mb*32 + (r0 & 3) + 8*(r0 >> 2) + 4*h;
            union { f16_t f[2]; unsigned u; } pkv;
            pkv.f[0] = (f16_t)(oacc[mb][r0]   * invl);
            pkv.f[1] = (f16_t)(oacc[mb][r0+1] * invl);
            *(unsigned*)(sOw + l31*LDO + d) = pkv.u;
        }
    __asm__ volatile("s_waitcnt lgkmcnt(0)" ::: "memory");  // wave-local round-trip

    const size_t gb = ((size_t)sp*NROW + (size_t)b*SEQ + q0)*DIM;
    #pragma unroll
    for (int jj = 0; jj < 8; jj++) {
        const int c  = lane + 64*jj;
        const int q  = c >> 4;
        const int dc = (c & 15)*8;
        union { f16x4 v[2]; uint4 u; } o;
        o.v[0] = *(const f16x4*)(sOw + q*LDO + dc);
        o.v[1] = *(const f16x4*)(sOw + q*LDO + dc + 4);
        *(uint4*)(Opart + gb + (size_t)q*DIM + dc) = o.u;
    }
    if (h == 0)
        mlbuf[sp*NROW + b*SEQ + q0 + l31] = make_float2(mrun, lrun);
}

// ---------------------------------------------------------------------------
// Kernel 3: combine the KV-split partials.
// ---------------------------------------------------------------------------
__global__ __launch_bounds__(256) void combine_kernel(
    const f16_t* __restrict__ Opart, const float2* __restrict__ mlbuf,
    float* __restrict__ out)
{
    const int idx = blockIdx.x*256 + threadIdx.x;
    const int row = idx >> 4;
    const int d0  = (idx & 15) * 8;

    float m[NSPLIT], l[NSPLIT];
    #pragma unroll
    for (int s = 0; s < NSPLIT; s++) {
        const float2 v = mlbuf[s*NROW + row];
        m[s] = v.x; l[s] = v.y;
    }
    float M = m[0];
    #pragma unroll
    for (int s = 1; s < NSPLIT; s++) M = fmaxf(M, m[s]);
    float w[NSPLIT], denom = 0.f;
    #pragma unroll
    for (int s = 0; s < NSPLIT; s++) {
        w[s] = l[s] * __builtin_amdgcn_exp2f(m[s] - M);
        denom += w[s];
    }
    const float inv = 1.f / denom;

    float o[8] = {0,0,0,0,0,0,0,0};
    #pragma unroll
    for (int s = 0; s < NSPLIT; s++) {
        const f16x8 v = *(const f16x8*)(Opart + ((size_t)s*NROW + row)*DIM + d0);
        const float ws = w[s] * inv;
        #pragma unroll
        for (int j = 0; j < 8; j++) o[j] += ws * (float)v[j];
    }
    float* ob = out + (size_t)row*DIM + d0;
    *(float4*)(ob)     = make_float4(o[0], o[1], o[2], o[3]);
    *(float4*)(ob + 4) = make_float4(o[4], o[5], o[6], o[7]);
}

// ---------------------------------------------------------------------------
extern "C" void kernel_launch(void* const* d_in, const int* in_sizes, int n_in,
                              void* d_out, int out_size, void* d_ws, size_t ws_size,
                              hipStream_t stream) {
    const float* x  = (const float*)d_in[0];
    // d_in[1] = token_attention_masks (unused: reference softmaxes UNMASKED scores)
    const float* wq = (const float*)d_in[2];
    const float* wk = (const float*)d_in[3];
    const float* wv = (const float*)d_in[4];

    f16_t* ws = (f16_t*)d_ws;
    f16_t* Qh    = ws;                                    // NROW*DIM each
    f16_t* Kh    = Qh  + (size_t)NROW*DIM;
    f16_t* Vt    = Kh  + (size_t)NROW*DIM;                // [B][D][S]
    f16_t* Opart = Vt  + (size_t)NROW*DIM;                // NSPLIT x NROW x DIM
    float2* mlbuf = (float2*)(Opart + (size_t)NSPLIT*NROW*DIM);

    proj_kernel   <<<(NROW/64)*3,           256, 0, stream>>>(x, wq, wk, wv, Qh, Kh, Vt);
    flash_kernel  <<<BATCH*(SEQ/128)*NSPLIT,256, 0, stream>>>(Qh, Kh, Vt, Opart, mlbuf);
    combine_kernel<<<NROW*DIM/8/256,        256, 0, stream>>>(Opart, mlbuf, (float*)d_out);
}